// Round 1
// baseline (2691.273 us; speedup 1.0000x reference)
//
#include <hip/hip_runtime.h>
#include <cmath>

#define B_   32
#define S_   128
#define E_   300
#define C_   100
#define EC_  50
#define LC_  50
#define H_   256
#define G4_  1024   // 4*H
#define L_   17
#define DHID_ 400   // E + C
#define NBLK 32     // lstm blocks per direction
#define HSL_ 8      // hidden slice per lstm block

// ---------------------------------------------------------------- init
__global__ void k_init(const float* __restrict__ h0, float* __restrict__ hbuf,
                       int* __restrict__ flags) {
  int tid = blockIdx.x * 256 + threadIdx.x;
  if (tid < 2 * B_ * H_) {
    int d = tid / (B_ * H_);
    int rem = tid % (B_ * H_);
    int b = rem / H_, k = rem % H_;
    // hbuf layout [d][t][k][b]
    hbuf[(((size_t)d * (S_ + 1)) * H_ + k) * B_ + b] = h0[tid];
  }
  if (tid < 2 * (S_ + 1)) {
    flags[tid] = (tid % (S_ + 1) == 0) ? NBLK : 0;
  }
}

// ---------------------------------------------------------------- char conv1
__global__ void k_conv1(const int* __restrict__ x_char, const float* __restrict__ char_emb,
                        const float* __restrict__ w1, const float* __restrict__ b1,
                        float* __restrict__ out1) {
  int b = blockIdx.x;        // 0..31
  int ot = blockIdx.y;       // 0..1 (tiles of 50 out channels)
  __shared__ float ce[EC_ * 52];     // [ec][t], pad 52
  __shared__ float wl[50 * 150];     // [o_local][c*3+k]
  __shared__ int ids[LC_];
  int tid = threadIdx.x;
  if (tid < LC_) ids[tid] = x_char[b * LC_ + tid];
  __syncthreads();
  for (int idx = tid; idx < LC_ * EC_; idx += 256) {
    int t = idx / EC_, ec = idx % EC_;
    ce[ec * 52 + t] = char_emb[ids[t] * EC_ + ec];
  }
  int obase = ot * 50;
  for (int idx = tid; idx < 50 * 150; idx += 256)
    wl[idx] = w1[obase * 150 + idx];
  __syncthreads();
  for (int idx = tid; idx < 50 * 48; idx += 256) {
    int o = idx / 48, t = idx % 48;
    float acc = b1[obase + o];
    const float* wr = &wl[o * 150];
    for (int c = 0; c < EC_; ++c) {
      const float* ip = &ce[c * 52 + t];
      acc += wr[c * 3 + 0] * ip[0] + wr[c * 3 + 1] * ip[1] + wr[c * 3 + 2] * ip[2];
    }
    out1[((size_t)b * C_ + obase + o) * 48 + t] = fmaxf(acc, 0.0f);
  }
}

// ---------------------------------------------------------------- char conv2
__global__ void k_conv2(const float* __restrict__ in, const float* __restrict__ w2,
                        const float* __restrict__ b2, float* __restrict__ out2) {
  int b = blockIdx.x, ot = blockIdx.y;  // 4 tiles of 25
  __shared__ float il[C_ * 48];
  __shared__ float wl[25 * 400];
  int tid = threadIdx.x;
  for (int idx = tid; idx < C_ * 48; idx += 256) il[idx] = in[(size_t)b * C_ * 48 + idx];
  int obase = ot * 25;
  for (int idx = tid; idx < 25 * 400; idx += 256) wl[idx] = w2[obase * 400 + idx];
  __syncthreads();
  for (int idx = tid; idx < 25 * 45; idx += 256) {
    int o = idx / 45, t = idx % 45;
    float acc = b2[obase + o];
    const float* wr = &wl[o * 400];
    for (int c = 0; c < C_; ++c) {
      const float* ip = &il[c * 48 + t];
      acc += wr[c * 4 + 0] * ip[0] + wr[c * 4 + 1] * ip[1] +
             wr[c * 4 + 2] * ip[2] + wr[c * 4 + 3] * ip[3];
    }
    out2[((size_t)b * C_ + obase + o) * 45 + t] = fmaxf(acc, 0.0f);
  }
}

// ---------------------------------------------------------------- char conv3 + maxpool
__global__ void k_conv3(const float* __restrict__ in, const float* __restrict__ w3,
                        const float* __restrict__ b3, float* __restrict__ pooled) {
  int b = blockIdx.x, ot = blockIdx.y;  // 5 tiles of 20
  __shared__ float il[C_ * 45];
  __shared__ float wl[20 * 500];
  __shared__ float o3[20 * 44];
  int tid = threadIdx.x;
  for (int idx = tid; idx < C_ * 45; idx += 256) il[idx] = in[(size_t)b * C_ * 45 + idx];
  int obase = ot * 20;
  for (int idx = tid; idx < 20 * 500; idx += 256) wl[idx] = w3[obase * 500 + idx];
  __syncthreads();
  for (int idx = tid; idx < 20 * 41; idx += 256) {
    int o = idx / 41, t = idx % 41;
    float acc = b3[obase + o];
    const float* wr = &wl[o * 500];
    for (int c = 0; c < C_; ++c) {
      const float* ip = &il[c * 45 + t];
      acc += wr[c * 5 + 0] * ip[0] + wr[c * 5 + 1] * ip[1] + wr[c * 5 + 2] * ip[2] +
             wr[c * 5 + 3] * ip[3] + wr[c * 5 + 4] * ip[4];
    }
    o3[o * 44 + t] = fmaxf(acc, 0.0f);
  }
  __syncthreads();
  if (tid < 20) {
    float m = o3[tid * 44];
    for (int t = 1; t < 41; ++t) m = fmaxf(m, o3[tid * 44 + t]);
    pooled[b * C_ + obase + tid] = m;
  }
}

// ---------------------------------------------------------------- effective bias (b + pooled @ W2^T)
__global__ void k_biaseff(const float* __restrict__ pooled,
                          const float* __restrict__ w_ih_f, const float* __restrict__ b_f,
                          const float* __restrict__ w_ih_b, const float* __restrict__ b_b,
                          float* __restrict__ biaseff) {
  int b = blockIdx.x, d = blockIdx.y;
  const float* wih = d ? w_ih_b : w_ih_f;
  const float* bb = d ? b_b : b_f;
  __shared__ float pl[C_];
  int tid = threadIdx.x;
  if (tid < C_) pl[tid] = pooled[b * C_ + tid];
  __syncthreads();
  for (int j = tid; j < G4_; j += 256) {
    float acc = bb[j];
    const float* wr = &wih[(size_t)j * DHID_ + E_];
    for (int c = 0; c < C_; ++c) acc += pl[c] * wr[c];
    biaseff[((size_t)d * B_ + b) * G4_ + j] = acc;
  }
}

// ---------------------------------------------------------------- input GEMM: gi[d][t][b][j] = emb . W1^T + biaseff
__global__ __launch_bounds__(256) void k_gemm_in(
    const int* __restrict__ x, const float* __restrict__ word_emb,
    const float* __restrict__ w_ih_f, const float* __restrict__ w_ih_b,
    const float* __restrict__ biaseff, float* __restrict__ gi) {
  int jt = blockIdx.x;   // 8  -> j0 = jt*128
  int rt = blockIdx.y;   // 32 -> r0 = rt*128  (r = t*32 + b)
  int d = blockIdx.z;
  const float* wih = d ? w_ih_b : w_ih_f;
  __shared__ float Al[16][132];
  __shared__ float Bl[16][132];
  __shared__ int wid[128];
  int tid = threadIdx.x;
  int r0 = rt * 128, j0 = jt * 128;
  if (tid < 128) {
    int r = r0 + tid;
    int t = r >> 5, b = r & 31;
    wid[tid] = x[b * S_ + t];
  }
  __syncthreads();
  float acc[8][8];
#pragma unroll
  for (int i = 0; i < 8; ++i)
#pragma unroll
    for (int j = 0; j < 8; ++j) acc[i][j] = 0.f;
  int ty = tid >> 4, tx = tid & 15;

  for (int k0 = 0; k0 < 304; k0 += 16) {
#pragma unroll
    for (int i = 0; i < 2; ++i) {
      int f = tid + i * 256;
      int rl = f >> 2, kc = f & 3;
      const float* src = word_emb + (size_t)wid[rl] * E_;
#pragma unroll
      for (int e = 0; e < 4; ++e) {
        int k = k0 + kc * 4 + e;
        float v = src[k < E_ ? k : (E_ - 1)];
        Al[kc * 4 + e][rl] = (k < E_) ? v : 0.f;
      }
    }
#pragma unroll
    for (int i = 0; i < 2; ++i) {
      int f = tid + i * 256;
      int jl = f >> 2, kc = f & 3;
      const float* src = wih + (size_t)(j0 + jl) * DHID_;
#pragma unroll
      for (int e = 0; e < 4; ++e) {
        int k = k0 + kc * 4 + e;
        float v = src[k];  // always in-bounds (row len 400)
        Bl[kc * 4 + e][jl] = (k < E_) ? v : 0.f;
      }
    }
    __syncthreads();
#pragma unroll
    for (int kk = 0; kk < 16; ++kk) {
      float4 a0 = *(const float4*)(&Al[kk][ty * 8]);
      float4 a1 = *(const float4*)(&Al[kk][ty * 8 + 4]);
      float4 b0 = *(const float4*)(&Bl[kk][tx * 8]);
      float4 b1 = *(const float4*)(&Bl[kk][tx * 8 + 4]);
      float av[8] = {a0.x, a0.y, a0.z, a0.w, a1.x, a1.y, a1.z, a1.w};
      float bv[8] = {b0.x, b0.y, b0.z, b0.w, b1.x, b1.y, b1.z, b1.w};
#pragma unroll
      for (int i = 0; i < 8; ++i)
#pragma unroll
        for (int j = 0; j < 8; ++j) acc[i][j] = fmaf(av[i], bv[j], acc[i][j]);
    }
    __syncthreads();
  }
#pragma unroll
  for (int i = 0; i < 8; ++i) {
    int r = r0 + ty * 8 + i;
    int b = r & 31;
    const float* be = biaseff + ((size_t)d * B_ + b) * G4_ + j0 + tx * 8;
    float* dst = gi + ((size_t)d * 4096 + r) * G4_ + j0 + tx * 8;
    float4 o0, o1;
    o0.x = acc[i][0] + be[0]; o0.y = acc[i][1] + be[1];
    o0.z = acc[i][2] + be[2]; o0.w = acc[i][3] + be[3];
    o1.x = acc[i][4] + be[4]; o1.y = acc[i][5] + be[5];
    o1.z = acc[i][6] + be[6]; o1.w = acc[i][7] + be[7];
    *(float4*)(dst) = o0;
    *(float4*)(dst + 4) = o1;
  }
}

// ---------------------------------------------------------------- BiLSTM recurrence
// grid (NBLK, 2); block 256. Block owns hidden slice [iblk*8, iblk*8+8) for all 32 batches.
// Cross-block h exchange: per-step buffers hbuf[d][t][k][b] + monotonic flags.
__global__ __launch_bounds__(256) void k_lstm(
    const float* __restrict__ w_hh_f, const float* __restrict__ w_hh_b,
    const float* __restrict__ c0, const float* __restrict__ gi,
    float* __restrict__ hbuf, int* __restrict__ flags) {
  const int iblk = blockIdx.x;
  const int d = blockIdx.y;
  const float* whh = d ? w_hh_b : w_hh_f;
  __shared__ float hl[H_ * B_];       // [k][b], xor-swizzled float4 slots; 32 KB
  __shared__ float gl[32 * 33];       // [jj][b]
  __shared__ float cl[HSL_ * B_];     // [kl][b]
  const int tid = threadIdx.x;
  const int ks = tid & 7;             // K-chunk (32 k each)
  const int jl = tid >> 3;            // local gate row 0..31
  const int gate = jl >> 3, klj = jl & 7;
  const int jg = gate * H_ + iblk * HSL_ + klj;  // global gate row

  float wreg[32];
  {
    const float* wr = whh + (size_t)jg * H_ + ks * 32;
#pragma unroll
    for (int kk = 0; kk < 32; ++kk) wreg[kk] = wr[kk];
  }
  const int cb = tid & 31, ckl = tid >> 5;
  cl[ckl * B_ + cb] = c0[((size_t)d * B_ + cb) * H_ + iblk * HSL_ + ckl];
  __syncthreads();

  for (int t = 0; t < S_; ++t) {
    if (tid == 0) {
      while (__hip_atomic_load(&flags[d * (S_ + 1) + t], __ATOMIC_RELAXED,
                               __HIP_MEMORY_SCOPE_AGENT) < NBLK)
        __builtin_amdgcn_s_sleep(1);
    }
    __syncthreads();
    __builtin_amdgcn_fence(__ATOMIC_ACQUIRE, "agent");

    // stage h[d][t][*][*] into LDS (straight copy; xor-swizzle slot for conflict-free reads)
    const float* hsrc = hbuf + ((size_t)d * (S_ + 1) + t) * (H_ * B_);
#pragma unroll
    for (int i = 0; i < 8; ++i) {
      int f = tid + i * 256;          // float4 id
      int k = f >> 3, b4 = f & 7;
      float4 v = *(const float4*)(hsrc + (size_t)f * 4);
      *(float4*)(&hl[(k << 5) + ((b4 ^ ((k >> 5) & 7)) << 2)]) = v;
    }
    // prefetch gi for this lane's b-range (ks*4..ks*4+3) at gate row jg
    int torig = d ? (S_ - 1 - t) : t;
    const float* gib = gi + ((size_t)d * S_ + torig) * ((size_t)B_ * G4_);
    float gv[4];
#pragma unroll
    for (int e = 0; e < 4; ++e) gv[e] = gib[(size_t)(ks * 4 + e) * G4_ + jg];
    __syncthreads();

    // partial dot over this lane's 32-k chunk, all 32 batches
    float acc[8][4];
#pragma unroll
    for (int b4 = 0; b4 < 8; ++b4) {
      acc[b4][0] = 0.f; acc[b4][1] = 0.f; acc[b4][2] = 0.f; acc[b4][3] = 0.f;
    }
    const int sw = ks;  // (k>>5)&7 for k in this chunk
#pragma unroll 4
    for (int kk = 0; kk < 32; ++kk) {
      int k = ks * 32 + kk;
      float w = wreg[kk];
      int row = k << 5;
#pragma unroll
      for (int b4 = 0; b4 < 8; ++b4) {
        const float4 hv = *(const float4*)(&hl[row + ((b4 ^ sw) << 2)]);
        acc[b4][0] = fmaf(w, hv.x, acc[b4][0]);
        acc[b4][1] = fmaf(w, hv.y, acc[b4][1]);
        acc[b4][2] = fmaf(w, hv.z, acc[b4][2]);
        acc[b4][3] = fmaf(w, hv.w, acc[b4][3]);
      }
    }
    // reduce across the 8 ks-lanes (lane bits 0..2), keep b-group == ks
    float g4[4];
#pragma unroll
    for (int b4 = 0; b4 < 8; ++b4) {
#pragma unroll
      for (int e = 0; e < 4; ++e) {
        float v = acc[b4][e];
        v += __shfl_xor(v, 1, 64);
        v += __shfl_xor(v, 2, 64);
        v += __shfl_xor(v, 4, 64);
        if (b4 == ks) g4[e] = v + gv[e];
      }
    }
#pragma unroll
    for (int e = 0; e < 4; ++e) gl[jl * 33 + ks * 4 + e] = g4[e];
    __syncthreads();

    // cell update: thread (cb = b, ckl = local k)
    {
      float gi_ = gl[(0 * 8 + ckl) * 33 + cb];
      float gf_ = gl[(1 * 8 + ckl) * 33 + cb];
      float gg_ = gl[(2 * 8 + ckl) * 33 + cb];
      float go_ = gl[(3 * 8 + ckl) * 33 + cb];
      float c = cl[ckl * B_ + cb];
      float si = 1.f / (1.f + expf(-gi_));
      float sf = 1.f / (1.f + expf(-gf_));
      float so = 1.f / (1.f + expf(-go_));
      float tg = tanhf(gg_);
      float cn = sf * c + si * tg;
      float hn = so * tanhf(cn);
      cl[ckl * B_ + cb] = cn;
      hbuf[(((size_t)d * (S_ + 1) + t + 1) * H_ + iblk * HSL_ + ckl) * B_ + cb] = hn;
    }
    __builtin_amdgcn_fence(__ATOMIC_RELEASE, "agent");
    __syncthreads();
    if (tid == 0)
      __hip_atomic_fetch_add(&flags[d * (S_ + 1) + t + 1], 1, __ATOMIC_RELAXED,
                             __HIP_MEMORY_SCOPE_AGENT);
  }
}

// ---------------------------------------------------------------- FC -> emissions em[b][s][l]
__global__ void k_fc(const float* __restrict__ hbuf, const float* __restrict__ fc_w,
                     const float* __restrict__ fc_b, float* __restrict__ em) {
  int idx = blockIdx.x * 256 + threadIdx.x;
  if (idx >= B_ * S_ * L_) return;
  int l = idx % L_;
  int bs = idx / L_;
  int s = bs % S_;
  int b = bs / S_;
  const float* hf = hbuf + ((size_t)(s + 1)) * (H_ * B_);
  const float* hb = hbuf + ((size_t)(S_ + 1) + (S_ - s)) * ((size_t)H_ * B_);
  const float* w = fc_w + (size_t)l * (2 * H_);
  float acc = fc_b[l];
  for (int k = 0; k < H_; ++k) acc = fmaf(hf[k * B_ + b], w[k], acc);
  for (int k = 0; k < H_; ++k) acc = fmaf(hb[k * B_ + b], w[H_ + k], acc);
  em[(size_t)idx] = acc;
}

// ---------------------------------------------------------------- softmax over SEQ dim (faithful)
__global__ void k_softmax(float* __restrict__ em) {
  int b = blockIdx.x;
  __shared__ float e[S_ * L_];
  int tid = threadIdx.x;
  for (int i = tid; i < S_ * L_; i += 256) e[i] = em[(size_t)b * S_ * L_ + i];
  __syncthreads();
  if (tid < L_) {
    int l = tid;
    float m = -INFINITY;
    for (int s = 0; s < S_; ++s) m = fmaxf(m, e[s * L_ + l]);
    float sum = 0.f;
    for (int s = 0; s < S_; ++s) {
      float ex = expf(e[s * L_ + l] - m);
      e[s * L_ + l] = ex;
      sum += ex;
    }
    for (int s = 0; s < S_; ++s) e[s * L_ + l] = e[s * L_ + l] / sum;
  }
  __syncthreads();
  for (int i = tid; i < S_ * L_; i += 256) em[(size_t)b * S_ * L_ + i] = e[i];
}

// ---------------------------------------------------------------- Viterbi (one block per batch)
__global__ void k_viterbi(const float* __restrict__ em, const int* __restrict__ x,
                          const float* __restrict__ start_t, const float* __restrict__ trans,
                          const float* __restrict__ end_t, int* __restrict__ hist,
                          int* __restrict__ out) {
  int b = blockIdx.x;
  __shared__ float tr[L_ * L_];
  __shared__ float sc[2][L_];
  int tid = threadIdx.x;
  for (int i = tid; i < L_ * L_; i += 64) tr[i] = trans[i];
  if (tid < L_) sc[0][tid] = start_t[tid] + em[((size_t)b * S_ + 0) * L_ + tid];
  __syncthreads();
  int cb = 0;
  for (int t = 1; t < S_; ++t) {
    if (tid < L_) {
      int j = tid;
      float e = em[((size_t)b * S_ + t) * L_ + j];
      float best = -INFINITY;
      int arg = 0;
      for (int i = 0; i < L_; ++i) {
        float v = (sc[cb][i] + tr[i * L_ + j]) + e;
        if (v > best) { best = v; arg = i; }  // strict >: first occurrence like np.argmax
      }
      int maskt = (x[b * S_ + t] != 0);
      sc[cb ^ 1][j] = maskt ? best : sc[cb][j];
      hist[((size_t)(t - 1) * B_ + b) * L_ + j] = arg;
    }
    __syncthreads();
    cb ^= 1;
  }
  __syncthreads();
  if (tid == 0) {
    float best = -INFINITY;
    int last = 0;
    for (int j = 0; j < L_; ++j) {
      float v = sc[cb][j] + end_t[j];
      if (v > best) { best = v; last = j; }
    }
    int cur = last;
    out[b * S_ + S_ - 1] = cur;
    for (int p = S_ - 2; p >= 0; --p) {
      if (x[b * S_ + p + 1] != 0) cur = hist[((size_t)p * B_ + b) * L_ + cur];
      out[b * S_ + p] = cur;
    }
  }
}

// ---------------------------------------------------------------- launch
extern "C" void kernel_launch(void* const* d_in, const int* in_sizes, int n_in,
                              void* d_out, int out_size, void* d_ws, size_t ws_size,
                              hipStream_t stream) {
  const int* x        = (const int*)d_in[0];
  const int* x_char   = (const int*)d_in[1];
  const float* word_emb = (const float*)d_in[2];
  const float* char_emb = (const float*)d_in[3];
  const float* conv1_w = (const float*)d_in[4];
  const float* conv1_b = (const float*)d_in[5];
  const float* conv2_w = (const float*)d_in[6];
  const float* conv2_b = (const float*)d_in[7];
  const float* conv3_w = (const float*)d_in[8];
  const float* conv3_b = (const float*)d_in[9];
  const float* w_ih_f = (const float*)d_in[10];
  const float* w_hh_f = (const float*)d_in[11];
  const float* b_f    = (const float*)d_in[12];
  const float* w_ih_b = (const float*)d_in[13];
  const float* w_hh_b = (const float*)d_in[14];
  const float* b_b    = (const float*)d_in[15];
  const float* h0     = (const float*)d_in[16];
  const float* c0     = (const float*)d_in[17];
  const float* fc_w   = (const float*)d_in[18];
  const float* fc_b   = (const float*)d_in[19];
  const float* start_t = (const float*)d_in[20];
  const float* trans  = (const float*)d_in[21];
  const float* end_t  = (const float*)d_in[22];
  int* out = (int*)d_out;

  char* ws = (char*)d_ws;
  auto alloc = [&](size_t bytes) -> char* {
    char* p = ws;
    ws += (bytes + 1023) & ~(size_t)1023;
    return p;
  };
  float* pooled  = (float*)alloc(sizeof(float) * B_ * C_);
  float* biaseff = (float*)alloc(sizeof(float) * 2 * B_ * G4_);
  float* gi      = (float*)alloc(sizeof(float) * 2 * S_ * B_ * G4_);    // 33.5 MB
  float* hbuf    = (float*)alloc(sizeof(float) * 2 * (S_ + 1) * H_ * B_); // 8.45 MB
  float* out1    = (float*)alloc(sizeof(float) * B_ * C_ * 48);
  float* out2    = (float*)alloc(sizeof(float) * B_ * C_ * 45);
  float* em      = (float*)alloc(sizeof(float) * B_ * S_ * L_);
  int* flags     = (int*)alloc(sizeof(int) * 2 * (S_ + 1));
  int* hist      = (int*)alloc(sizeof(int) * (S_ - 1) * B_ * L_);

  k_init<<<64, 256, 0, stream>>>(h0, hbuf, flags);
  k_conv1<<<dim3(32, 2), 256, 0, stream>>>(x_char, char_emb, conv1_w, conv1_b, out1);
  k_conv2<<<dim3(32, 4), 256, 0, stream>>>(out1, conv2_w, conv2_b, out2);
  k_conv3<<<dim3(32, 5), 256, 0, stream>>>(out2, conv3_w, conv3_b, pooled);
  k_biaseff<<<dim3(32, 2), 256, 0, stream>>>(pooled, w_ih_f, b_f, w_ih_b, b_b, biaseff);
  k_gemm_in<<<dim3(8, 32, 2), 256, 0, stream>>>(x, word_emb, w_ih_f, w_ih_b, biaseff, gi);
  k_lstm<<<dim3(NBLK, 2), 256, 0, stream>>>(w_hh_f, w_hh_b, c0, gi, hbuf, flags);
  k_fc<<<(B_ * S_ * L_ + 255) / 256, 256, 0, stream>>>(hbuf, fc_w, fc_b, em);
  k_softmax<<<32, 256, 0, stream>>>(em);
  k_viterbi<<<32, 64, 0, stream>>>(em, x, start_t, trans, end_t, hist, out);
}

// Round 2
// 2077.248 us; speedup vs baseline: 1.2956x; 1.2956x over previous
//
#include <hip/hip_runtime.h>
#include <cmath>

#define B_   32
#define S_   128
#define E_   300
#define C_   100
#define EC_  50
#define LC_  50
#define H_   256
#define G4_  1024   // 4*H
#define L_   17
#define DHID_ 400   // E + C
#define NBLK 32     // lstm blocks per direction
#define HSL_ 8      // hidden slice per lstm block
#define SENT_ 0x7FC00000u  // qNaN sentinel: real h is sigmoid*tanh, never NaN

// ---------------------------------------------------------------- hbuf init: t=0 from h0, t>=1 sentinel
__global__ void k_hinit(const float* __restrict__ h0, unsigned* __restrict__ hbuf) {
  int idx = blockIdx.x * 256 + threadIdx.x;
  const int per_d = (S_ + 1) * H_ * B_;
  if (idx >= 2 * per_d) return;
  int d = idx / per_d;
  int rem = idx % per_d;
  int t = rem / (H_ * B_);
  if (t == 0) {
    int kb = rem % (H_ * B_);
    int k = kb >> 5, b = kb & 31;
    hbuf[idx] = __float_as_uint(h0[(d * B_ + b) * H_ + k]);
  } else {
    hbuf[idx] = SENT_;
  }
}

// ---------------------------------------------------------------- char conv1
__global__ void k_conv1(const int* __restrict__ x_char, const float* __restrict__ char_emb,
                        const float* __restrict__ w1, const float* __restrict__ b1,
                        float* __restrict__ out1) {
  int b = blockIdx.x;        // 0..31
  int ot = blockIdx.y;       // 0..1 (tiles of 50 out channels)
  __shared__ float ce[EC_ * 52];     // [ec][t], pad 52
  __shared__ float wl[50 * 150];     // [o_local][c*3+k]
  __shared__ int ids[LC_];
  int tid = threadIdx.x;
  if (tid < LC_) ids[tid] = x_char[b * LC_ + tid];
  __syncthreads();
  for (int idx = tid; idx < LC_ * EC_; idx += 256) {
    int t = idx / EC_, ec = idx % EC_;
    ce[ec * 52 + t] = char_emb[ids[t] * EC_ + ec];
  }
  int obase = ot * 50;
  for (int idx = tid; idx < 50 * 150; idx += 256)
    wl[idx] = w1[obase * 150 + idx];
  __syncthreads();
  for (int idx = tid; idx < 50 * 48; idx += 256) {
    int o = idx / 48, t = idx % 48;
    float acc = b1[obase + o];
    const float* wr = &wl[o * 150];
    for (int c = 0; c < EC_; ++c) {
      const float* ip = &ce[c * 52 + t];
      acc += wr[c * 3 + 0] * ip[0] + wr[c * 3 + 1] * ip[1] + wr[c * 3 + 2] * ip[2];
    }
    out1[((size_t)b * C_ + obase + o) * 48 + t] = fmaxf(acc, 0.0f);
  }
}

// ---------------------------------------------------------------- char conv2
__global__ void k_conv2(const float* __restrict__ in, const float* __restrict__ w2,
                        const float* __restrict__ b2, float* __restrict__ out2) {
  int b = blockIdx.x, ot = blockIdx.y;  // 4 tiles of 25
  __shared__ float il[C_ * 48];
  __shared__ float wl[25 * 400];
  int tid = threadIdx.x;
  for (int idx = tid; idx < C_ * 48; idx += 256) il[idx] = in[(size_t)b * C_ * 48 + idx];
  int obase = ot * 25;
  for (int idx = tid; idx < 25 * 400; idx += 256) wl[idx] = w2[obase * 400 + idx];
  __syncthreads();
  for (int idx = tid; idx < 25 * 45; idx += 256) {
    int o = idx / 45, t = idx % 45;
    float acc = b2[obase + o];
    const float* wr = &wl[o * 400];
    for (int c = 0; c < C_; ++c) {
      const float* ip = &il[c * 48 + t];
      acc += wr[c * 4 + 0] * ip[0] + wr[c * 4 + 1] * ip[1] +
             wr[c * 4 + 2] * ip[2] + wr[c * 4 + 3] * ip[3];
    }
    out2[((size_t)b * C_ + obase + o) * 45 + t] = fmaxf(acc, 0.0f);
  }
}

// ---------------------------------------------------------------- char conv3 + maxpool
__global__ void k_conv3(const float* __restrict__ in, const float* __restrict__ w3,
                        const float* __restrict__ b3, float* __restrict__ pooled) {
  int b = blockIdx.x, ot = blockIdx.y;  // 5 tiles of 20
  __shared__ float il[C_ * 45];
  __shared__ float wl[20 * 500];
  __shared__ float o3[20 * 44];
  int tid = threadIdx.x;
  for (int idx = tid; idx < C_ * 45; idx += 256) il[idx] = in[(size_t)b * C_ * 45 + idx];
  int obase = ot * 20;
  for (int idx = tid; idx < 20 * 500; idx += 256) wl[idx] = w3[obase * 500 + idx];
  __syncthreads();
  for (int idx = tid; idx < 20 * 41; idx += 256) {
    int o = idx / 41, t = idx % 41;
    float acc = b3[obase + o];
    const float* wr = &wl[o * 500];
    for (int c = 0; c < C_; ++c) {
      const float* ip = &il[c * 45 + t];
      acc += wr[c * 5 + 0] * ip[0] + wr[c * 5 + 1] * ip[1] + wr[c * 5 + 2] * ip[2] +
             wr[c * 5 + 3] * ip[3] + wr[c * 5 + 4] * ip[4];
    }
    o3[o * 44 + t] = fmaxf(acc, 0.0f);
  }
  __syncthreads();
  if (tid < 20) {
    float m = o3[tid * 44];
    for (int t = 1; t < 41; ++t) m = fmaxf(m, o3[tid * 44 + t]);
    pooled[b * C_ + obase + tid] = m;
  }
}

// ---------------------------------------------------------------- effective bias -> [d][j][b]
__global__ void k_biaseff(const float* __restrict__ pooled,
                          const float* __restrict__ w_ih_f, const float* __restrict__ b_f,
                          const float* __restrict__ w_ih_b, const float* __restrict__ b_b,
                          float* __restrict__ biaseff) {
  int b = blockIdx.x, d = blockIdx.y;
  const float* wih = d ? w_ih_b : w_ih_f;
  const float* bb = d ? b_b : b_f;
  __shared__ float pl[C_];
  int tid = threadIdx.x;
  if (tid < C_) pl[tid] = pooled[b * C_ + tid];
  __syncthreads();
  for (int j = tid; j < G4_; j += 256) {
    float acc = bb[j];
    const float* wr = &wih[(size_t)j * DHID_ + E_];
    for (int c = 0; c < C_; ++c) acc += pl[c] * wr[c];
    biaseff[((size_t)d * G4_ + j) * B_ + b] = acc;
  }
}

// ---------------------------------------------------------------- input GEMM -> gi[d][t][j][b]
__global__ __launch_bounds__(256) void k_gemm_in(
    const int* __restrict__ x, const float* __restrict__ word_emb,
    const float* __restrict__ w_ih_f, const float* __restrict__ w_ih_b,
    const float* __restrict__ biaseff, float* __restrict__ gi) {
  int jt = blockIdx.x;   // 8  -> j0 = jt*128
  int rt = blockIdx.y;   // 32 -> r0 = rt*128  (r = t*32 + b)
  int d = blockIdx.z;
  const float* wih = d ? w_ih_b : w_ih_f;
  __shared__ float Al[16][132];
  __shared__ float Bl[16][132];
  __shared__ int wid[128];
  int tid = threadIdx.x;
  int r0 = rt * 128, j0 = jt * 128;
  if (tid < 128) {
    int r = r0 + tid;
    int t = r >> 5, b = r & 31;
    wid[tid] = x[b * S_ + t];
  }
  __syncthreads();
  float acc[8][8];
#pragma unroll
  for (int i = 0; i < 8; ++i)
#pragma unroll
    for (int j = 0; j < 8; ++j) acc[i][j] = 0.f;
  int ty = tid >> 4, tx = tid & 15;

  for (int k0 = 0; k0 < 304; k0 += 16) {
#pragma unroll
    for (int i = 0; i < 2; ++i) {
      int f = tid + i * 256;
      int rl = f >> 2, kc = f & 3;
      const float* src = word_emb + (size_t)wid[rl] * E_;
#pragma unroll
      for (int e = 0; e < 4; ++e) {
        int k = k0 + kc * 4 + e;
        float v = src[k < E_ ? k : (E_ - 1)];
        Al[kc * 4 + e][rl] = (k < E_) ? v : 0.f;
      }
    }
#pragma unroll
    for (int i = 0; i < 2; ++i) {
      int f = tid + i * 256;
      int jl = f >> 2, kc = f & 3;
      const float* src = wih + (size_t)(j0 + jl) * DHID_;
#pragma unroll
      for (int e = 0; e < 4; ++e) {
        int k = k0 + kc * 4 + e;
        float v = src[k];  // row len 400, always in-bounds
        Bl[kc * 4 + e][jl] = (k < E_) ? v : 0.f;
      }
    }
    __syncthreads();
#pragma unroll
    for (int kk = 0; kk < 16; ++kk) {
      float4 a0 = *(const float4*)(&Al[kk][ty * 8]);
      float4 a1 = *(const float4*)(&Al[kk][ty * 8 + 4]);
      float4 b0 = *(const float4*)(&Bl[kk][tx * 8]);
      float4 b1 = *(const float4*)(&Bl[kk][tx * 8 + 4]);
      float av[8] = {a0.x, a0.y, a0.z, a0.w, a1.x, a1.y, a1.z, a1.w};
      float bv[8] = {b0.x, b0.y, b0.z, b0.w, b1.x, b1.y, b1.z, b1.w};
#pragma unroll
      for (int i = 0; i < 8; ++i)
#pragma unroll
        for (int j = 0; j < 8; ++j) acc[i][j] = fmaf(av[i], bv[j], acc[i][j]);
    }
    __syncthreads();
  }
  // epilogue: rows i map to b = b0 + i (fixed t); write gi[d][t][j][b] + biaseff[d][j][b]
  int b0 = (ty & 3) * 8;
  int tt = rt * 4 + (ty >> 2);
#pragma unroll
  for (int jj = 0; jj < 8; ++jj) {
    int j = j0 + tx * 8 + jj;
    const float* be = biaseff + ((size_t)d * G4_ + j) * B_ + b0;
    float4 bl = *(const float4*)(be);
    float4 bh = *(const float4*)(be + 4);
    float4 lo, hi;
    lo.x = acc[0][jj] + bl.x; lo.y = acc[1][jj] + bl.y;
    lo.z = acc[2][jj] + bl.z; lo.w = acc[3][jj] + bl.w;
    hi.x = acc[4][jj] + bh.x; hi.y = acc[5][jj] + bh.y;
    hi.z = acc[6][jj] + bh.z; hi.w = acc[7][jj] + bh.w;
    float* dst = gi + (((size_t)(d * S_ + tt) * G4_) + j) * B_ + b0;
    *(float4*)dst = lo;
    *(float4*)(dst + 4) = hi;
  }
}

// ---------------------------------------------------------------- BiLSTM recurrence, fence-free
// grid (NBLK, 2); block 256 = 1 CU each (64 blocks on 256 CUs).
// h exchange: sentinel-initialized per-step slices; producers publish via relaxed
// agent-scope atomic stores, consumers poll with relaxed agent-scope atomic loads.
// Data is its own flag -> no fences (no L2 writeback/invalidate on the critical path).
__global__ __launch_bounds__(256) void k_lstm(
    const float* __restrict__ w_hh_f, const float* __restrict__ w_hh_b,
    const float* __restrict__ c0, const float* __restrict__ gi,
    unsigned* __restrict__ hbuf) {
  const int iblk = blockIdx.x;
  const int d = blockIdx.y;
  const float* whh = d ? w_hh_b : w_hh_f;
  __shared__ float hl[H_ * B_];       // [k][b], xor-swizzled float4 slots; 32 KB
  __shared__ float gl[32 * 33];       // [jj][b]
  const int tid = threadIdx.x;
  const int ks = tid & 7;             // K-chunk (32 k each)
  const int jl = tid >> 3;            // local gate row 0..31
  const int gate = jl >> 3, klj = jl & 7;
  const int jg = gate * H_ + iblk * HSL_ + klj;  // global gate row

  float wreg[32];
  {
    const float* wr = whh + (size_t)jg * H_ + ks * 32;
#pragma unroll
    for (int kk = 0; kk < 32; ++kk) wreg[kk] = wr[kk];
  }
  // cell state in register: thread (ckl = tid>>5, cb = tid&31)
  const int cb = tid & 31, ckl = tid >> 5;
  float creg = c0[((size_t)d * B_ + cb) * H_ + iblk * HSL_ + ckl];

  for (int t = 0; t < S_; ++t) {
    // gate-input prefetch (independent of h) — gi[d][torig][jg][ks*4..+3]
    int torig = d ? (S_ - 1 - t) : t;
    const float4 gv4 = *(const float4*)(gi + (((size_t)(d * S_ + torig) * G4_) + jg) * B_ + ks * 4);

    // poll full h(t): element e = j*256 + tid (coalesced), e = k*32 + b
    const unsigned* hsrc = hbuf + ((size_t)(d * (S_ + 1) + t)) * (H_ * B_);
    unsigned hv[32];
#pragma unroll
    for (int j = 0; j < 32; ++j)
      hv[j] = __hip_atomic_load(&hsrc[j * 256 + tid], __ATOMIC_RELAXED,
                                __HIP_MEMORY_SCOPE_AGENT);
    for (;;) {
      bool pending = false;
#pragma unroll
      for (int j = 0; j < 32; ++j) pending = pending | (hv[j] == SENT_);
      if (!pending) break;
#pragma unroll
      for (int j = 0; j < 32; ++j)
        if (hv[j] == SENT_)
          hv[j] = __hip_atomic_load(&hsrc[j * 256 + tid], __ATOMIC_RELAXED,
                                    __HIP_MEMORY_SCOPE_AGENT);
    }
    // scatter to LDS with xor swizzle (2-way bank aliasing = free)
#pragma unroll
    for (int j = 0; j < 32; ++j) {
      int e = j * 256 + tid;
      int k = e >> 5, b = e & 31;
      int slot = (k << 5) + ((((b >> 2) ^ ((k >> 5) & 7)) << 2) | (b & 3));
      hl[slot] = __uint_as_float(hv[j]);
    }
    __syncthreads();

    // partial dot over this lane's 32-k chunk, all 32 batches
    float acc[8][4];
#pragma unroll
    for (int b4 = 0; b4 < 8; ++b4) {
      acc[b4][0] = 0.f; acc[b4][1] = 0.f; acc[b4][2] = 0.f; acc[b4][3] = 0.f;
    }
    const int sw = ks;
#pragma unroll 4
    for (int kk = 0; kk < 32; ++kk) {
      int k = ks * 32 + kk;
      float w = wreg[kk];
      int row = k << 5;
#pragma unroll
      for (int b4 = 0; b4 < 8; ++b4) {
        const float4 hvv = *(const float4*)(&hl[row + ((b4 ^ sw) << 2)]);
        acc[b4][0] = fmaf(w, hvv.x, acc[b4][0]);
        acc[b4][1] = fmaf(w, hvv.y, acc[b4][1]);
        acc[b4][2] = fmaf(w, hvv.z, acc[b4][2]);
        acc[b4][3] = fmaf(w, hvv.w, acc[b4][3]);
      }
    }
    // reduce across the 8 ks-lanes, keep b-group == ks; add gate input
    float g4[4];
#pragma unroll
    for (int b4 = 0; b4 < 8; ++b4) {
#pragma unroll
      for (int e = 0; e < 4; ++e) {
        float v = acc[b4][e];
        v += __shfl_xor(v, 1, 64);
        v += __shfl_xor(v, 2, 64);
        v += __shfl_xor(v, 4, 64);
        if (b4 == ks) g4[e] = v;
      }
    }
    g4[0] += gv4.x; g4[1] += gv4.y; g4[2] += gv4.z; g4[3] += gv4.w;
#pragma unroll
    for (int e = 0; e < 4; ++e) gl[jl * 33 + ks * 4 + e] = g4[e];
    __syncthreads();

    // cell update (c in register), publish h(t+1) via agent-scope atomic store
    {
      float gi_ = gl[(0 * 8 + ckl) * 33 + cb];
      float gf_ = gl[(1 * 8 + ckl) * 33 + cb];
      float gg_ = gl[(2 * 8 + ckl) * 33 + cb];
      float go_ = gl[(3 * 8 + ckl) * 33 + cb];
      float si = 1.f / (1.f + expf(-gi_));
      float sf = 1.f / (1.f + expf(-gf_));
      float so = 1.f / (1.f + expf(-go_));
      float tg = tanhf(gg_);
      float cn = sf * creg + si * tg;
      float hn = so * tanhf(cn);
      creg = cn;
      __hip_atomic_store(
          &hbuf[(((size_t)(d * (S_ + 1) + t + 1)) * H_ + iblk * HSL_ + ckl) * B_ + cb],
          __float_as_uint(hn), __ATOMIC_RELAXED, __HIP_MEMORY_SCOPE_AGENT);
    }
  }
}

// ---------------------------------------------------------------- FC -> emissions em[b][s][l]
__global__ void k_fc(const unsigned* __restrict__ hbuf_u, const float* __restrict__ fc_w,
                     const float* __restrict__ fc_b, float* __restrict__ em) {
  const float* hbuf = (const float*)hbuf_u;
  int idx = blockIdx.x * 256 + threadIdx.x;
  if (idx >= B_ * S_ * L_) return;
  int l = idx % L_;
  int bs = idx / L_;
  int s = bs % S_;
  int b = bs / S_;
  const float* hf = hbuf + ((size_t)(s + 1)) * (H_ * B_);
  const float* hb = hbuf + ((size_t)(S_ + 1) + (S_ - s)) * ((size_t)H_ * B_);
  const float* w = fc_w + (size_t)l * (2 * H_);
  float acc = fc_b[l];
  for (int k = 0; k < H_; ++k) acc = fmaf(hf[k * B_ + b], w[k], acc);
  for (int k = 0; k < H_; ++k) acc = fmaf(hb[k * B_ + b], w[H_ + k], acc);
  em[(size_t)idx] = acc;
}

// ---------------------------------------------------------------- softmax over SEQ dim (faithful)
__global__ void k_softmax(float* __restrict__ em) {
  int b = blockIdx.x;
  __shared__ float e[S_ * L_];
  int tid = threadIdx.x;
  for (int i = tid; i < S_ * L_; i += 256) e[i] = em[(size_t)b * S_ * L_ + i];
  __syncthreads();
  if (tid < L_) {
    int l = tid;
    float m = -INFINITY;
    for (int s = 0; s < S_; ++s) m = fmaxf(m, e[s * L_ + l]);
    float sum = 0.f;
    for (int s = 0; s < S_; ++s) {
      float ex = expf(e[s * L_ + l] - m);
      e[s * L_ + l] = ex;
      sum += ex;
    }
    for (int s = 0; s < S_; ++s) e[s * L_ + l] = e[s * L_ + l] / sum;
  }
  __syncthreads();
  for (int i = tid; i < S_ * L_; i += 256) em[(size_t)b * S_ * L_ + i] = e[i];
}

// ---------------------------------------------------------------- Viterbi (one block per batch)
__global__ void k_viterbi(const float* __restrict__ em, const int* __restrict__ x,
                          const float* __restrict__ start_t, const float* __restrict__ trans,
                          const float* __restrict__ end_t, int* __restrict__ hist,
                          int* __restrict__ out) {
  int b = blockIdx.x;
  __shared__ float tr[L_ * L_];
  __shared__ float sc[2][L_];
  int tid = threadIdx.x;
  for (int i = tid; i < L_ * L_; i += 64) tr[i] = trans[i];
  if (tid < L_) sc[0][tid] = start_t[tid] + em[((size_t)b * S_ + 0) * L_ + tid];
  __syncthreads();
  int cbuf = 0;
  for (int t = 1; t < S_; ++t) {
    if (tid < L_) {
      int j = tid;
      float e = em[((size_t)b * S_ + t) * L_ + j];
      float best = -INFINITY;
      int arg = 0;
      for (int i = 0; i < L_; ++i) {
        float v = (sc[cbuf][i] + tr[i * L_ + j]) + e;
        if (v > best) { best = v; arg = i; }  // strict >: first occurrence like np.argmax
      }
      int maskt = (x[b * S_ + t] != 0);
      sc[cbuf ^ 1][j] = maskt ? best : sc[cbuf][j];
      hist[((size_t)(t - 1) * B_ + b) * L_ + j] = arg;
    }
    __syncthreads();
    cbuf ^= 1;
  }
  __syncthreads();
  if (tid == 0) {
    float best = -INFINITY;
    int last = 0;
    for (int j = 0; j < L_; ++j) {
      float v = sc[cbuf][j] + end_t[j];
      if (v > best) { best = v; last = j; }
    }
    int cur = last;
    out[b * S_ + S_ - 1] = cur;
    for (int p = S_ - 2; p >= 0; --p) {
      if (x[b * S_ + p + 1] != 0) cur = hist[((size_t)p * B_ + b) * L_ + cur];
      out[b * S_ + p] = cur;
    }
  }
}

// ---------------------------------------------------------------- launch
extern "C" void kernel_launch(void* const* d_in, const int* in_sizes, int n_in,
                              void* d_out, int out_size, void* d_ws, size_t ws_size,
                              hipStream_t stream) {
  const int* x        = (const int*)d_in[0];
  const int* x_char   = (const int*)d_in[1];
  const float* word_emb = (const float*)d_in[2];
  const float* char_emb = (const float*)d_in[3];
  const float* conv1_w = (const float*)d_in[4];
  const float* conv1_b = (const float*)d_in[5];
  const float* conv2_w = (const float*)d_in[6];
  const float* conv2_b = (const float*)d_in[7];
  const float* conv3_w = (const float*)d_in[8];
  const float* conv3_b = (const float*)d_in[9];
  const float* w_ih_f = (const float*)d_in[10];
  const float* w_hh_f = (const float*)d_in[11];
  const float* b_f    = (const float*)d_in[12];
  const float* w_ih_b = (const float*)d_in[13];
  const float* w_hh_b = (const float*)d_in[14];
  const float* b_b    = (const float*)d_in[15];
  const float* h0     = (const float*)d_in[16];
  const float* c0     = (const float*)d_in[17];
  const float* fc_w   = (const float*)d_in[18];
  const float* fc_b   = (const float*)d_in[19];
  const float* start_t = (const float*)d_in[20];
  const float* trans  = (const float*)d_in[21];
  const float* end_t  = (const float*)d_in[22];
  int* out = (int*)d_out;

  char* ws = (char*)d_ws;
  auto alloc = [&](size_t bytes) -> char* {
    char* p = ws;
    ws += (bytes + 1023) & ~(size_t)1023;
    return p;
  };
  float* pooled  = (float*)alloc(sizeof(float) * B_ * C_);
  float* biaseff = (float*)alloc(sizeof(float) * 2 * G4_ * B_);
  float* gi      = (float*)alloc(sizeof(float) * 2 * S_ * G4_ * B_);      // 33.5 MB
  unsigned* hbuf = (unsigned*)alloc(sizeof(unsigned) * 2 * (S_ + 1) * H_ * B_); // 8.45 MB
  float* out1    = (float*)alloc(sizeof(float) * B_ * C_ * 48);
  float* out2    = (float*)alloc(sizeof(float) * B_ * C_ * 45);
  float* em      = (float*)alloc(sizeof(float) * B_ * S_ * L_);
  int* hist      = (int*)alloc(sizeof(int) * (S_ - 1) * B_ * L_);

  const int hinit_total = 2 * (S_ + 1) * H_ * B_;
  k_hinit<<<(hinit_total + 255) / 256, 256, 0, stream>>>(h0, hbuf);
  k_conv1<<<dim3(32, 2), 256, 0, stream>>>(x_char, char_emb, conv1_w, conv1_b, out1);
  k_conv2<<<dim3(32, 4), 256, 0, stream>>>(out1, conv2_w, conv2_b, out2);
  k_conv3<<<dim3(32, 5), 256, 0, stream>>>(out2, conv3_w, conv3_b, pooled);
  k_biaseff<<<dim3(32, 2), 256, 0, stream>>>(pooled, w_ih_f, b_f, w_ih_b, b_b, biaseff);
  k_gemm_in<<<dim3(8, 32, 2), 256, 0, stream>>>(x, word_emb, w_ih_f, w_ih_b, biaseff, gi);
  k_lstm<<<dim3(NBLK, 2), 256, 0, stream>>>(w_hh_f, w_hh_b, c0, gi, hbuf);
  k_fc<<<(B_ * S_ * L_ + 255) / 256, 256, 0, stream>>>(hbuf, fc_w, fc_b, em);
  k_softmax<<<32, 256, 0, stream>>>(em);
  k_viterbi<<<32, 64, 0, stream>>>(em, x, start_t, trans, end_t, hist, out);
}

// Round 3
// 1250.066 us; speedup vs baseline: 2.1529x; 1.6617x over previous
//
#include <hip/hip_runtime.h>
#include <cmath>

#define B_   32
#define S_   128
#define E_   300
#define C_   100
#define EC_  50
#define LC_  50
#define H_   256
#define G4_  1024   // 4*H
#define L_   17
#define DHID_ 400   // E + C
#define NBLKD 8     // lstm blocks per direction
#define SENT2_ 0x7E007E00u  // fp16-NaN in both halves: legit packed h never matches

typedef _Float16 half8 __attribute__((ext_vector_type(8)));
typedef float f32x4 __attribute__((ext_vector_type(4)));

// split fp32 -> (hi fp16, lo fp16 scaled by 2048), packed u32 (hi in low16).
// subnormal-safe: tiny values go entirely into lo (which is then normal).
__device__ __forceinline__ unsigned pack_split(float v) {
  _Float16 hi = (fabsf(v) >= 6.104e-5f) ? (_Float16)v : (_Float16)0.0f;
  float hif = (float)hi;
  _Float16 lo = (_Float16)((v - hif) * 2048.0f);
  return (unsigned)__builtin_bit_cast(unsigned short, hi)
       | ((unsigned)__builtin_bit_cast(unsigned short, lo) << 16);
}

// ---------------------------------------------------------------- hpack init: t=0 from h0, t>=1 sentinel
__global__ void k_hinit(const float* __restrict__ h0, unsigned* __restrict__ hpack) {
  int idx = blockIdx.x * 256 + threadIdx.x;
  const int per_d = (S_ + 1) * H_ * B_;
  if (idx >= 2 * per_d) return;
  int d = idx / per_d;
  int rem = idx % per_d;
  int t = rem / (H_ * B_);
  if (t == 0) {
    int bk = rem % (H_ * B_);   // plane layout [b][k]
    int b = bk >> 8, k = bk & 255;
    hpack[idx] = pack_split(h0[(d * B_ + b) * H_ + k]);
  } else {
    hpack[idx] = SENT2_;
  }
}

// ---------------------------------------------------------------- char conv1
__global__ void k_conv1(const int* __restrict__ x_char, const float* __restrict__ char_emb,
                        const float* __restrict__ w1, const float* __restrict__ b1,
                        float* __restrict__ out1) {
  int b = blockIdx.x;
  int ot = blockIdx.y;
  __shared__ float ce[EC_ * 52];
  __shared__ float wl[50 * 150];
  __shared__ int ids[LC_];
  int tid = threadIdx.x;
  if (tid < LC_) ids[tid] = x_char[b * LC_ + tid];
  __syncthreads();
  for (int idx = tid; idx < LC_ * EC_; idx += 256) {
    int t = idx / EC_, ec = idx % EC_;
    ce[ec * 52 + t] = char_emb[ids[t] * EC_ + ec];
  }
  int obase = ot * 50;
  for (int idx = tid; idx < 50 * 150; idx += 256)
    wl[idx] = w1[obase * 150 + idx];
  __syncthreads();
  for (int idx = tid; idx < 50 * 48; idx += 256) {
    int o = idx / 48, t = idx % 48;
    float acc = b1[obase + o];
    const float* wr = &wl[o * 150];
    for (int c = 0; c < EC_; ++c) {
      const float* ip = &ce[c * 52 + t];
      acc += wr[c * 3 + 0] * ip[0] + wr[c * 3 + 1] * ip[1] + wr[c * 3 + 2] * ip[2];
    }
    out1[((size_t)b * C_ + obase + o) * 48 + t] = fmaxf(acc, 0.0f);
  }
}

// ---------------------------------------------------------------- char conv2
__global__ void k_conv2(const float* __restrict__ in, const float* __restrict__ w2,
                        const float* __restrict__ b2, float* __restrict__ out2) {
  int b = blockIdx.x, ot = blockIdx.y;
  __shared__ float il[C_ * 48];
  __shared__ float wl[25 * 400];
  int tid = threadIdx.x;
  for (int idx = tid; idx < C_ * 48; idx += 256) il[idx] = in[(size_t)b * C_ * 48 + idx];
  int obase = ot * 25;
  for (int idx = tid; idx < 25 * 400; idx += 256) wl[idx] = w2[obase * 400 + idx];
  __syncthreads();
  for (int idx = tid; idx < 25 * 45; idx += 256) {
    int o = idx / 45, t = idx % 45;
    float acc = b2[obase + o];
    const float* wr = &wl[o * 400];
    for (int c = 0; c < C_; ++c) {
      const float* ip = &il[c * 48 + t];
      acc += wr[c * 4 + 0] * ip[0] + wr[c * 4 + 1] * ip[1] +
             wr[c * 4 + 2] * ip[2] + wr[c * 4 + 3] * ip[3];
    }
    out2[((size_t)b * C_ + obase + o) * 45 + t] = fmaxf(acc, 0.0f);
  }
}

// ---------------------------------------------------------------- char conv3 + maxpool
__global__ void k_conv3(const float* __restrict__ in, const float* __restrict__ w3,
                        const float* __restrict__ b3, float* __restrict__ pooled) {
  int b = blockIdx.x, ot = blockIdx.y;
  __shared__ float il[C_ * 45];
  __shared__ float wl[20 * 500];
  __shared__ float o3[20 * 44];
  int tid = threadIdx.x;
  for (int idx = tid; idx < C_ * 45; idx += 256) il[idx] = in[(size_t)b * C_ * 45 + idx];
  int obase = ot * 20;
  for (int idx = tid; idx < 20 * 500; idx += 256) wl[idx] = w3[obase * 500 + idx];
  __syncthreads();
  for (int idx = tid; idx < 20 * 41; idx += 256) {
    int o = idx / 41, t = idx % 41;
    float acc = b3[obase + o];
    const float* wr = &wl[o * 500];
    for (int c = 0; c < C_; ++c) {
      const float* ip = &il[c * 45 + t];
      acc += wr[c * 5 + 0] * ip[0] + wr[c * 5 + 1] * ip[1] + wr[c * 5 + 2] * ip[2] +
             wr[c * 5 + 3] * ip[3] + wr[c * 5 + 4] * ip[4];
    }
    o3[o * 44 + t] = fmaxf(acc, 0.0f);
  }
  __syncthreads();
  if (tid < 20) {
    float m = o3[tid * 44];
    for (int t = 1; t < 41; ++t) m = fmaxf(m, o3[tid * 44 + t]);
    pooled[b * C_ + obase + tid] = m;
  }
}

// ---------------------------------------------------------------- effective bias -> [d][j][b]
__global__ void k_biaseff(const float* __restrict__ pooled,
                          const float* __restrict__ w_ih_f, const float* __restrict__ b_f,
                          const float* __restrict__ w_ih_b, const float* __restrict__ b_b,
                          float* __restrict__ biaseff) {
  int b = blockIdx.x, d = blockIdx.y;
  const float* wih = d ? w_ih_b : w_ih_f;
  const float* bb = d ? b_b : b_f;
  __shared__ float pl[C_];
  int tid = threadIdx.x;
  if (tid < C_) pl[tid] = pooled[b * C_ + tid];
  __syncthreads();
  for (int j = tid; j < G4_; j += 256) {
    float acc = bb[j];
    const float* wr = &wih[(size_t)j * DHID_ + E_];
    for (int c = 0; c < C_; ++c) acc += pl[c] * wr[c];
    biaseff[((size_t)d * G4_ + j) * B_ + b] = acc;
  }
}

// ---------------------------------------------------------------- input GEMM -> gi[d][t][j][b]
__global__ __launch_bounds__(256) void k_gemm_in(
    const int* __restrict__ x, const float* __restrict__ word_emb,
    const float* __restrict__ w_ih_f, const float* __restrict__ w_ih_b,
    const float* __restrict__ biaseff, float* __restrict__ gi) {
  int jt = blockIdx.x;
  int rt = blockIdx.y;
  int d = blockIdx.z;
  const float* wih = d ? w_ih_b : w_ih_f;
  __shared__ float Al[16][132];
  __shared__ float Bl[16][132];
  __shared__ int wid[128];
  int tid = threadIdx.x;
  int r0 = rt * 128, j0 = jt * 128;
  if (tid < 128) {
    int r = r0 + tid;
    int t = r >> 5, b = r & 31;
    wid[tid] = x[b * S_ + t];
  }
  __syncthreads();
  float acc[8][8];
#pragma unroll
  for (int i = 0; i < 8; ++i)
#pragma unroll
    for (int j = 0; j < 8; ++j) acc[i][j] = 0.f;
  int ty = tid >> 4, tx = tid & 15;

  for (int k0 = 0; k0 < 304; k0 += 16) {
#pragma unroll
    for (int i = 0; i < 2; ++i) {
      int f = tid + i * 256;
      int rl = f >> 2, kc = f & 3;
      const float* src = word_emb + (size_t)wid[rl] * E_;
#pragma unroll
      for (int e = 0; e < 4; ++e) {
        int k = k0 + kc * 4 + e;
        float v = src[k < E_ ? k : (E_ - 1)];
        Al[kc * 4 + e][rl] = (k < E_) ? v : 0.f;
      }
    }
#pragma unroll
    for (int i = 0; i < 2; ++i) {
      int f = tid + i * 256;
      int jl = f >> 2, kc = f & 3;
      const float* src = wih + (size_t)(j0 + jl) * DHID_;
#pragma unroll
      for (int e = 0; e < 4; ++e) {
        int k = k0 + kc * 4 + e;
        float v = src[k];
        Bl[kc * 4 + e][jl] = (k < E_) ? v : 0.f;
      }
    }
    __syncthreads();
#pragma unroll
    for (int kk = 0; kk < 16; ++kk) {
      float4 a0 = *(const float4*)(&Al[kk][ty * 8]);
      float4 a1 = *(const float4*)(&Al[kk][ty * 8 + 4]);
      float4 b0 = *(const float4*)(&Bl[kk][tx * 8]);
      float4 b1 = *(const float4*)(&Bl[kk][tx * 8 + 4]);
      float av[8] = {a0.x, a0.y, a0.z, a0.w, a1.x, a1.y, a1.z, a1.w};
      float bv[8] = {b0.x, b0.y, b0.z, b0.w, b1.x, b1.y, b1.z, b1.w};
#pragma unroll
      for (int i = 0; i < 8; ++i)
#pragma unroll
        for (int j = 0; j < 8; ++j) acc[i][j] = fmaf(av[i], bv[j], acc[i][j]);
    }
    __syncthreads();
  }
  int b0 = (ty & 3) * 8;
  int tt = rt * 4 + (ty >> 2);
#pragma unroll
  for (int jj = 0; jj < 8; ++jj) {
    int j = j0 + tx * 8 + jj;
    const float* be = biaseff + ((size_t)d * G4_ + j) * B_ + b0;
    float4 bl = *(const float4*)(be);
    float4 bh = *(const float4*)(be + 4);
    float4 lo, hi;
    lo.x = acc[0][jj] + bl.x; lo.y = acc[1][jj] + bl.y;
    lo.z = acc[2][jj] + bl.z; lo.w = acc[3][jj] + bl.w;
    hi.x = acc[4][jj] + bh.x; hi.y = acc[5][jj] + bh.y;
    hi.z = acc[6][jj] + bh.z; hi.w = acc[7][jj] + bh.w;
    float* dst = gi + (((size_t)(d * S_ + tt) * G4_) + j) * B_ + b0;
    *(float4*)dst = lo;
    *(float4*)(dst + 4) = hi;
  }
}

// ---------------------------------------------------------------- BiLSTM recurrence via MFMA fp16x2
// grid (NBLKD, 2); block 256 (4 waves). Wave w = gate w; block owns h-units [iblk*32, iblk*32+32).
// W_hh fragments persistent in registers as fp16 hi/lo(x2048) splits; gates accumulate in fp32 MFMA.
// h exchange: packed (hi|lo) u32 planes, sentinel-polled, relaxed agent-scope atomics (fence-free).
__global__ __launch_bounds__(256, 1) void k_lstm(
    const float* __restrict__ w_hh_f, const float* __restrict__ w_hh_b,
    const float* __restrict__ c0, const float* __restrict__ gi,
    float* __restrict__ hbuf, unsigned* __restrict__ hpack) {
  const int iblk = blockIdx.x;     // 0..7
  const int d = blockIdx.y;
  const float* whh = d ? w_hh_b : w_hh_f;
  const int tid = threadIdx.x;
  const int w = tid >> 6;          // wave index = gate (i,f,g,o)
  const int l = tid & 63;
  const int lx = l & 15, lq = l >> 4;
  const int u0 = iblk * 32;

  __shared__ unsigned hlds[32 * 260];   // [b][k] packed h, stride 260 (conflict-free b128 reads)
  __shared__ float gl[4 * 32 * 33];     // [gate][u][b]

  // ---- persistent W fragments: A-layout A[m=lane&15][k=(lane>>4)*8+j]
  half8 whi[2][8], wlo[2][8];
#pragma unroll
  for (int Mt = 0; Mt < 2; ++Mt) {
#pragma unroll
    for (int Kt = 0; Kt < 8; ++Kt) {
      int row = w * H_ + u0 + Mt * 16 + lx;
      int kk0 = Kt * 32 + lq * 8;
      const float* src = whh + (size_t)row * H_ + kk0;
      float4 f0 = *(const float4*)src;
      float4 f1 = *(const float4*)(src + 4);
      float wv[8] = {f0.x, f0.y, f0.z, f0.w, f1.x, f1.y, f1.z, f1.w};
      union { unsigned short s[8]; half8 h; } HI, LO;
#pragma unroll
      for (int j = 0; j < 8; ++j) {
        float v = wv[j];
        _Float16 hi = (fabsf(v) >= 6.104e-5f) ? (_Float16)v : (_Float16)0.0f;
        float hif = (float)hi;
        _Float16 lo = (_Float16)((v - hif) * 2048.0f);
        HI.s[j] = __builtin_bit_cast(unsigned short, hi);
        LO.s[j] = __builtin_bit_cast(unsigned short, lo);
      }
      whi[Mt][Kt] = HI.h;
      wlo[Mt][Kt] = LO.h;
    }
  }

  // cell state: thread (bc = tid&31, cw = tid>>5) owns u = cu*8+cw for cu=0..3
  const int bc = tid & 31, cw = tid >> 5;
  float creg[4];
#pragma unroll
  for (int cu = 0; cu < 4; ++cu)
    creg[cu] = c0[((size_t)d * B_ + bc) * H_ + u0 + cu * 8 + cw];

  const float inv2048 = 1.0f / 2048.0f;

  for (int t = 0; t < S_; ++t) {
    int torig = d ? (S_ - 1 - t) : t;

    // gate-input frags (independent of h): init acc_hi with gi (C-operand trick)
    f32x4 acch[2][2], accl[2][2];
    {
      const float* gbase = gi + ((size_t)(d * S_ + torig) * G4_) * B_;
#pragma unroll
      for (int Mt = 0; Mt < 2; ++Mt)
#pragma unroll
        for (int Nt = 0; Nt < 2; ++Nt) {
          f32x4 v;
#pragma unroll
          for (int r = 0; r < 4; ++r) {
            int j = w * H_ + u0 + Mt * 16 + lq * 4 + r;
            v[r] = gbase[(size_t)j * B_ + Nt * 16 + lx];
          }
          acch[Mt][Nt] = v;
          f32x4 z = {0.f, 0.f, 0.f, 0.f};
          accl[Mt][Nt] = z;
        }
    }

    // poll packed h(t): element flat = j*256 + tid -> b=j, k=tid (coalesced)
    const unsigned* hp = hpack + (size_t)(d * (S_ + 1) + t) * (H_ * B_);
    unsigned hv[32];
#pragma unroll
    for (int j = 0; j < 32; ++j)
      hv[j] = __hip_atomic_load(&hp[j * 256 + tid], __ATOMIC_RELAXED,
                                __HIP_MEMORY_SCOPE_AGENT);
    for (;;) {
      bool pending = false;
#pragma unroll
      for (int j = 0; j < 32; ++j) pending = pending | (hv[j] == SENT2_);
      if (!pending) break;
#pragma unroll
      for (int j = 0; j < 32; ++j)
        if (hv[j] == SENT2_)
          hv[j] = __hip_atomic_load(&hp[j * 256 + tid], __ATOMIC_RELAXED,
                                    __HIP_MEMORY_SCOPE_AGENT);
    }
    // scatter to hlds[b][k]: banks = tid%32 -> 2-way (free)
#pragma unroll
    for (int j = 0; j < 32; ++j) hlds[j * 260 + tid] = hv[j];
    __syncthreads();

    // MFMA: gates += Whi.Hhi (acch) ; Whi.Hlo + Wlo.Hhi (accl, x2048)
#pragma unroll
    for (int Kt = 0; Kt < 8; ++Kt) {
      half8 Bhi[2], Blo[2];
#pragma unroll
      for (int Nt = 0; Nt < 2; ++Nt) {
        int bb = Nt * 16 + lx;
        const unsigned* p = &hlds[bb * 260 + Kt * 32 + lq * 8];
        uint4 a = *(const uint4*)p;
        uint4 b2 = *(const uint4*)(p + 4);
        union { unsigned q[4]; half8 h; } BH, BL;
        BH.q[0] = (a.x & 0xFFFFu) | (a.y << 16);
        BH.q[1] = (a.z & 0xFFFFu) | (a.w << 16);
        BH.q[2] = (b2.x & 0xFFFFu) | (b2.y << 16);
        BH.q[3] = (b2.z & 0xFFFFu) | (b2.w << 16);
        BL.q[0] = (a.x >> 16) | (a.y & 0xFFFF0000u);
        BL.q[1] = (a.z >> 16) | (a.w & 0xFFFF0000u);
        BL.q[2] = (b2.x >> 16) | (b2.y & 0xFFFF0000u);
        BL.q[3] = (b2.z >> 16) | (b2.w & 0xFFFF0000u);
        Bhi[Nt] = BH.h;
        Blo[Nt] = BL.h;
      }
#pragma unroll
      for (int Mt = 0; Mt < 2; ++Mt)
#pragma unroll
        for (int Nt = 0; Nt < 2; ++Nt) {
          acch[Mt][Nt] = __builtin_amdgcn_mfma_f32_16x16x32_f16(
              whi[Mt][Kt], Bhi[Nt], acch[Mt][Nt], 0, 0, 0);
          accl[Mt][Nt] = __builtin_amdgcn_mfma_f32_16x16x32_f16(
              whi[Mt][Kt], Blo[Nt], accl[Mt][Nt], 0, 0, 0);
          accl[Mt][Nt] = __builtin_amdgcn_mfma_f32_16x16x32_f16(
              wlo[Mt][Kt], Bhi[Nt], accl[Mt][Nt], 0, 0, 0);
        }
    }

    // gates -> gl ; C/D layout: col=lane&15, row=(lane>>4)*4+reg
#pragma unroll
    for (int Mt = 0; Mt < 2; ++Mt)
#pragma unroll
      for (int Nt = 0; Nt < 2; ++Nt)
#pragma unroll
        for (int r = 0; r < 4; ++r) {
          int ul = Mt * 16 + lq * 4 + r;
          gl[(w * 32 + ul) * 33 + Nt * 16 + lx] =
              acch[Mt][Nt][r] + accl[Mt][Nt][r] * inv2048;
        }
    __syncthreads();

    // cell update + publish
#pragma unroll
    for (int cu = 0; cu < 4; ++cu) {
      int u = cu * 8 + cw;
      float g_i = gl[(0 * 32 + u) * 33 + bc];
      float g_f = gl[(1 * 32 + u) * 33 + bc];
      float g_g = gl[(2 * 32 + u) * 33 + bc];
      float g_o = gl[(3 * 32 + u) * 33 + bc];
      float si = 1.f / (1.f + expf(-g_i));
      float sf = 1.f / (1.f + expf(-g_f));
      float so = 1.f / (1.f + expf(-g_o));
      float tg = tanhf(g_g);
      float cn = sf * creg[cu] + si * tg;
      float hn = so * tanhf(cn);
      creg[cu] = cn;
      hbuf[((size_t)(d * (S_ + 1) + t + 1) * H_ + u0 + u) * B_ + bc] = hn;
      __hip_atomic_store(
          &hpack[(size_t)(d * (S_ + 1) + t + 1) * (H_ * B_) + bc * 256 + u0 + u],
          pack_split(hn), __ATOMIC_RELAXED, __HIP_MEMORY_SCOPE_AGENT);
    }
  }
}

// ---------------------------------------------------------------- FC -> emissions em[b][s][l]
__global__ void k_fc(const float* __restrict__ hbuf, const float* __restrict__ fc_w,
                     const float* __restrict__ fc_b, float* __restrict__ em) {
  int idx = blockIdx.x * 256 + threadIdx.x;
  if (idx >= B_ * S_ * L_) return;
  int l = idx % L_;
  int bs = idx / L_;
  int s = bs % S_;
  int b = bs / S_;
  const float* hf = hbuf + ((size_t)(s + 1)) * (H_ * B_);
  const float* hb = hbuf + ((size_t)(S_ + 1) + (S_ - s)) * ((size_t)H_ * B_);
  const float* w = fc_w + (size_t)l * (2 * H_);
  float acc = fc_b[l];
  for (int k = 0; k < H_; ++k) acc = fmaf(hf[k * B_ + b], w[k], acc);
  for (int k = 0; k < H_; ++k) acc = fmaf(hb[k * B_ + b], w[H_ + k], acc);
  em[(size_t)idx] = acc;
}

// ---------------------------------------------------------------- softmax over SEQ dim (faithful)
__global__ void k_softmax(float* __restrict__ em) {
  int b = blockIdx.x;
  __shared__ float e[S_ * L_];
  int tid = threadIdx.x;
  for (int i = tid; i < S_ * L_; i += 256) e[i] = em[(size_t)b * S_ * L_ + i];
  __syncthreads();
  if (tid < L_) {
    int l = tid;
    float m = -INFINITY;
    for (int s = 0; s < S_; ++s) m = fmaxf(m, e[s * L_ + l]);
    float sum = 0.f;
    for (int s = 0; s < S_; ++s) {
      float ex = expf(e[s * L_ + l] - m);
      e[s * L_ + l] = ex;
      sum += ex;
    }
    for (int s = 0; s < S_; ++s) e[s * L_ + l] = e[s * L_ + l] / sum;
  }
  __syncthreads();
  for (int i = tid; i < S_ * L_; i += 256) em[(size_t)b * S_ * L_ + i] = e[i];
}

// ---------------------------------------------------------------- Viterbi (one block per batch)
__global__ void k_viterbi(const float* __restrict__ em, const int* __restrict__ x,
                          const float* __restrict__ start_t, const float* __restrict__ trans,
                          const float* __restrict__ end_t, int* __restrict__ hist,
                          int* __restrict__ out) {
  int b = blockIdx.x;
  __shared__ float tr[L_ * L_];
  __shared__ float sc[2][L_];
  int tid = threadIdx.x;
  for (int i = tid; i < L_ * L_; i += 64) tr[i] = trans[i];
  if (tid < L_) sc[0][tid] = start_t[tid] + em[((size_t)b * S_ + 0) * L_ + tid];
  __syncthreads();
  int cbuf = 0;
  for (int t = 1; t < S_; ++t) {
    if (tid < L_) {
      int j = tid;
      float e = em[((size_t)b * S_ + t) * L_ + j];
      float best = -INFINITY;
      int arg = 0;
      for (int i = 0; i < L_; ++i) {
        float v = (sc[cbuf][i] + tr[i * L_ + j]) + e;
        if (v > best) { best = v; arg = i; }  // strict >: first occurrence like np.argmax
      }
      int maskt = (x[b * S_ + t] != 0);
      sc[cbuf ^ 1][j] = maskt ? best : sc[cbuf][j];
      hist[((size_t)(t - 1) * B_ + b) * L_ + j] = arg;
    }
    __syncthreads();
    cbuf ^= 1;
  }
  __syncthreads();
  if (tid == 0) {
    float best = -INFINITY;
    int last = 0;
    for (int j = 0; j < L_; ++j) {
      float v = sc[cbuf][j] + end_t[j];
      if (v > best) { best = v; last = j; }
    }
    int cur = last;
    out[b * S_ + S_ - 1] = cur;
    for (int p = S_ - 2; p >= 0; --p) {
      if (x[b * S_ + p + 1] != 0) cur = hist[((size_t)p * B_ + b) * L_ + cur];
      out[b * S_ + p] = cur;
    }
  }
}

// ---------------------------------------------------------------- launch
extern "C" void kernel_launch(void* const* d_in, const int* in_sizes, int n_in,
                              void* d_out, int out_size, void* d_ws, size_t ws_size,
                              hipStream_t stream) {
  const int* x        = (const int*)d_in[0];
  const int* x_char   = (const int*)d_in[1];
  const float* word_emb = (const float*)d_in[2];
  const float* char_emb = (const float*)d_in[3];
  const float* conv1_w = (const float*)d_in[4];
  const float* conv1_b = (const float*)d_in[5];
  const float* conv2_w = (const float*)d_in[6];
  const float* conv2_b = (const float*)d_in[7];
  const float* conv3_w = (const float*)d_in[8];
  const float* conv3_b = (const float*)d_in[9];
  const float* w_ih_f = (const float*)d_in[10];
  const float* w_hh_f = (const float*)d_in[11];
  const float* b_f    = (const float*)d_in[12];
  const float* w_ih_b = (const float*)d_in[13];
  const float* w_hh_b = (const float*)d_in[14];
  const float* b_b    = (const float*)d_in[15];
  const float* h0     = (const float*)d_in[16];
  const float* c0     = (const float*)d_in[17];
  const float* fc_w   = (const float*)d_in[18];
  const float* fc_b   = (const float*)d_in[19];
  const float* start_t = (const float*)d_in[20];
  const float* trans  = (const float*)d_in[21];
  const float* end_t  = (const float*)d_in[22];
  int* out = (int*)d_out;

  char* ws = (char*)d_ws;
  auto alloc = [&](size_t bytes) -> char* {
    char* p = ws;
    ws += (bytes + 1023) & ~(size_t)1023;
    return p;
  };
  float* pooled  = (float*)alloc(sizeof(float) * B_ * C_);
  float* biaseff = (float*)alloc(sizeof(float) * 2 * G4_ * B_);
  float* gi      = (float*)alloc(sizeof(float) * 2 * S_ * G4_ * B_);          // 33.5 MB
  float* hbuf    = (float*)alloc(sizeof(float) * 2 * (S_ + 1) * H_ * B_);     // 8.45 MB
  unsigned* hpack = (unsigned*)alloc(sizeof(unsigned) * 2 * (S_ + 1) * H_ * B_); // 8.45 MB
  float* out1    = (float*)alloc(sizeof(float) * B_ * C_ * 48);
  float* out2    = (float*)alloc(sizeof(float) * B_ * C_ * 45);
  float* em      = (float*)alloc(sizeof(float) * B_ * S_ * L_);
  int* hist      = (int*)alloc(sizeof(int) * (S_ - 1) * B_ * L_);

  const int hinit_total = 2 * (S_ + 1) * H_ * B_;
  k_hinit<<<(hinit_total + 255) / 256, 256, 0, stream>>>(h0, hpack);
  k_conv1<<<dim3(32, 2), 256, 0, stream>>>(x_char, char_emb, conv1_w, conv1_b, out1);
  k_conv2<<<dim3(32, 4), 256, 0, stream>>>(out1, conv2_w, conv2_b, out2);
  k_conv3<<<dim3(32, 5), 256, 0, stream>>>(out2, conv3_w, conv3_b, pooled);
  k_biaseff<<<dim3(32, 2), 256, 0, stream>>>(pooled, w_ih_f, b_f, w_ih_b, b_b, biaseff);
  k_gemm_in<<<dim3(8, 32, 2), 256, 0, stream>>>(x, word_emb, w_ih_f, w_ih_b, biaseff, gi);
  k_lstm<<<dim3(NBLKD, 2), 256, 0, stream>>>(w_hh_f, w_hh_b, c0, gi, hbuf, hpack);
  k_fc<<<(B_ * S_ * L_ + 255) / 256, 256, 0, stream>>>(hbuf, fc_w, fc_b, em);
  k_softmax<<<32, 256, 0, stream>>>(em);
  k_viterbi<<<32, 64, 0, stream>>>(em, x, start_t, trans, end_t, hist, out);
}